// Round 5
// baseline (180.446 us; speedup 1.0000x reference)
//
#include <hip/hip_runtime.h>
#include <hip/hip_bf16.h>
#include <stdint.h>
#include <type_traits>

// ---------------------------------------------------------------------------
// Fused attention: out = softmax((x Wq^T)(x Wk^T)^T / sqrt(d)) (x Wv^T)
// B=4, S=2048, D=1024, fp32 in/out, bf16 MFMA internal compute.
//
// R5: 2-tile-lead pipeline: during tile t (reading buf[t&1]) stage tile t+2
// into the SAME buffer's regions as the Gray-code phase order frees them
// (A0@ph1, B0@ph1, B1@ph2, A1@ph3). ONE counted wait per K-tile at end-ph3:
// vmcnt(2*(LA+LB)) — drains exactly tile t+1's loads, leaving t+2's 8 in
// flight. No mid-tile waits. Stage->consume distance ~5-7 phases.
// ---------------------------------------------------------------------------

typedef __attribute__((ext_vector_type(8))) short short8;
typedef __attribute__((ext_vector_type(4))) float f32x4;

#define GL_G(p) ((const __attribute__((address_space(1))) void*)(p))
#define GL_L(p) ((__attribute__((address_space(3))) void*)(p))

__device__ __forceinline__ float bf2f(unsigned short u) {
  union { float f; uint32_t i; } c; c.i = ((uint32_t)u) << 16; return c.f;
}
__device__ __forceinline__ unsigned short f2bf(float f) {
  __hip_bfloat16 h = __float2bfloat16(f);
  return *reinterpret_cast<unsigned short*>(&h);
}

// ---------------- cast fp32 -> bf16 (vectorized) ----------------
__global__ __launch_bounds__(256) void cast_f32_to_bf16(
    const float* __restrict__ in, unsigned short* __restrict__ out, long n) {
  long tid = (long)blockIdx.x * blockDim.x + threadIdx.x;
  long stride = (long)gridDim.x * blockDim.x;
  for (long j = tid * 8; j < n; j += stride * 8) {
    float4 a = *(const float4*)(in + j);
    float4 b = *(const float4*)(in + j + 4);
    uint4 pk;
    pk.x = (uint32_t)f2bf(a.x) | ((uint32_t)f2bf(a.y) << 16);
    pk.y = (uint32_t)f2bf(a.z) | ((uint32_t)f2bf(a.w) << 16);
    pk.z = (uint32_t)f2bf(b.x) | ((uint32_t)f2bf(b.y) << 16);
    pk.w = (uint32_t)f2bf(b.z) | ((uint32_t)f2bf(b.w) << 16);
    *(uint4*)(out + j) = pk;
  }
}

// fused 3-weight cast: Wq,Wk,Wv (each WE=2^20 elems) -> contiguous bf16
__global__ __launch_bounds__(256) void cast_w3(
    const float* __restrict__ wq, const float* __restrict__ wk,
    const float* __restrict__ wv, unsigned short* __restrict__ out) {
  const long WE = 1L << 20;
  long j = ((long)blockIdx.x * blockDim.x + threadIdx.x) * 8;
  if (j >= 3 * WE) return;
  int sel = (int)(j >> 20);
  const float* src = (sel == 0) ? wq : (sel == 1) ? wk : wv;
  long loc = j & (WE - 1);
  float4 a = *(const float4*)(src + loc);
  float4 b = *(const float4*)(src + loc + 4);
  uint4 pk;
  pk.x = (uint32_t)f2bf(a.x) | ((uint32_t)f2bf(a.y) << 16);
  pk.y = (uint32_t)f2bf(a.z) | ((uint32_t)f2bf(a.w) << 16);
  pk.z = (uint32_t)f2bf(b.x) | ((uint32_t)f2bf(b.y) << 16);
  pk.w = (uint32_t)f2bf(b.z) | ((uint32_t)f2bf(b.w) << 16);
  *(uint4*)(out + j) = pk;
}

template <int N>
__device__ __forceinline__ void waitv() {
  asm volatile("s_waitcnt vmcnt(%0)" :: "n"(N) : "memory");
}
__device__ __forceinline__ void barrier_() {
  asm volatile("" ::: "memory");
  __builtin_amdgcn_s_barrier();
  asm volatile("" ::: "memory");
}

// ---------------- NT GEMM, 256xBN tile, BK=64, 2-tile-lead pipeline -------
// C[m,n] = scale * sum_k A[m,k] B[n,k].  A:[M x K] bf16 (ldA), B:[N x K] (ldB)
// Requires M%256==0, N%BN==0, K%64==0, K/64 >= 2. Grid 1D = nbm*nbn*nz, %8==0.
// If z == ztrans (OUT_T must be ushort): store transposed per-batch
// (hardcoded: 2048 rows/batch, out [1024][2048] per batch).
template <int BN, typename OUT_T>
__global__ __launch_bounds__(512, 2) void gemm8p(
    const unsigned short* __restrict__ A, const unsigned short* __restrict__ B,
    OUT_T* __restrict__ C, int K, int ldA, int ldB, int ldC,
    long sA, long sB, long sC, float scale, int nbm, int nbn, int ztrans) {
  constexpr int BM = 256, BK = 64;
  constexpr int WVN = BN / 4;    // per-wave N: 64 or 32
  constexpr int NREP = WVN / 16; // 4 or 2
  constexpr int NPH = NREP / 2;  // frags per phase: 2 or 1
  constexpr int LA = 2;          // global_load_lds per A-half
  constexpr int LB = BN / 128;   // per B-half: 2 or 1
  constexpr int TL = 2 * (LA + LB);        // loads per K-tile (8 or 6)
  constexpr int AHALF = 128 * BK * 2;      // 16384 B
  constexpr int BHALF = (BN / 2) * BK * 2; // 16384 or 8192 B
  __shared__ __align__(16) char smem[4 * AHALF + 4 * BHALF];

  const int tid = threadIdx.x;
  const int wid = tid >> 6, lane = tid & 63;
  const int wm = wid >> 2, wn = wid & 3;
  const int fr = lane & 15;
  const int kq = lane >> 4;  // 0..3

  // XCD-aware bijective swizzle (gridDim %8==0), n-major decode.
  const int NB = gridDim.x;
  const int p = blockIdx.x;
  const int l = (p & 7) * (NB >> 3) + (p >> 3);
  const int pb = nbm * nbn;
  const int z = l / pb;
  const int mn = l - z * pb;
  const int bm = mn / nbn, bn = mn - bm * nbn;
  const unsigned short* Az = A + (long)z * sA;
  const unsigned short* Bz = B + (long)z * sB;
  const long brow = (long)bm * BM, bcol = (long)bn * BN;

  // staging: each load = 512 thr x 16B = 64 rows x 128B. source col is
  // pre-swizzled so linear LDS write == swizzled layout (m173/m201 pattern).
  const int srow = tid >> 3;  // 0..63
  const int scolb = ((tid & 7) * 16) ^ ((srow & 7) << 4);

  auto stageA = [&](int buf, int half, int kt) {
#pragma unroll
    for (int part = 0; part < LA; ++part) {
      const char* g = (const char*)Az +
          ((brow + half * 128 + part * 64 + srow) * (long)ldA + kt) * 2 + scolb;
      __builtin_amdgcn_global_load_lds(
          GL_G(g),
          GL_L(smem + (buf * 2 + half) * AHALF + part * 8192 + wid * 1024),
          16, 0, 0);
    }
  };
  auto stageB = [&](int buf, int half, int kt) {
#pragma unroll
    for (int part = 0; part < LB; ++part) {
      const char* g = (const char*)Bz +
          ((bcol + half * (BN / 2) + part * 64 + srow) * (long)ldB + kt) * 2 +
          scolb;
      __builtin_amdgcn_global_load_lds(
          GL_G(g),
          GL_L(smem + 4 * AHALF + (buf * 2 + half) * BHALF + part * 8192 +
               wid * 1024),
          16, 0, 0);
    }
  };

  f32x4 acc[8][NREP];
#pragma unroll
  for (int m = 0; m < 8; ++m)
#pragma unroll
    for (int n = 0; n < NREP; ++n) acc[m][n] = (f32x4){0.f, 0.f, 0.f, 0.f};

  short8 af[4][2];         // current A-half (reloaded ph0 / ph2)
  short8 b0[NPH][2];       // B-half 0 (read ph0, reused ph3)
  short8 b1[NPH][2];       // B-half 1 (read ph1, reused ph2)

  auto readA = [&](int cur, int mh) {
#pragma unroll
    for (int i = 0; i < 4; ++i)
#pragma unroll
      for (int ks = 0; ks < 2; ++ks) {
        const int r = wm * 64 + i * 16 + fr;
        const int off = (cur * 2 + mh) * AHALF + r * 128 +
                        ((ks * 64 + kq * 16) ^ ((fr & 7) << 4));
        af[i][ks] = *(const short8*)(smem + off);
      }
  };
  auto readB = [&](short8 (&bf_)[NPH][2], int cur, int nh) {
#pragma unroll
    for (int j = 0; j < NPH; ++j)
#pragma unroll
      for (int ks = 0; ks < 2; ++ks) {
        const int r = wn * (WVN / 2) + j * 16 + fr;
        const int off = 4 * AHALF + (cur * 2 + nh) * BHALF + r * 128 +
                        ((ks * 64 + kq * 16) ^ ((fr & 7) << 4));
        bf_[j][ks] = *(const short8*)(smem + off);
      }
  };
  auto mfmaCl = [&](int mh, int nh, short8 (&bf_)[NPH][2]) {
    __builtin_amdgcn_s_setprio(1);
#pragma unroll
    for (int i = 0; i < 4; ++i)
#pragma unroll
      for (int j = 0; j < NPH; ++j)
#pragma unroll
        for (int ks = 0; ks < 2; ++ks)
          acc[mh * 4 + i][nh * NPH + j] =
              __builtin_amdgcn_mfma_f32_16x16x32_bf16(
                  af[i][ks], bf_[j][ks], acc[mh * 4 + i][nh * NPH + j], 0, 0,
                  0);
    __builtin_amdgcn_s_setprio(0);
  };
  auto lgkm0sb = [&]() {
    asm volatile("s_waitcnt lgkmcnt(0)" ::: "memory");
    __builtin_amdgcn_sched_barrier(0);
  };

  // prologue: tiles 0 and 1 staged (buf0, buf1); drain tile 0 (vmcnt(TL)
  // leaves tile 1's TL loads in flight).
  stageA(0, 0, 0); stageB(0, 0, 0); stageB(0, 1, 0); stageA(0, 1, 0);
  stageA(1, 0, BK); stageB(1, 0, BK); stageB(1, 1, BK); stageA(1, 1, BK);
  waitv<TL>();
  barrier_();

  const int nt = K / BK;  // >= 2 required
  for (int t = 0; t < nt; ++t) {
    const int cur = t & 1;
    const int kt2 = (t + 2) * BK;
    const bool more2 = (t + 2) < nt;

    // ---- PH0: (mh=0, nh=0) — reads A0, B0 ----
    readA(cur, 0);
    readB(b0, cur, 0);
    barrier_();
    lgkm0sb();
    mfmaCl(0, 0, b0);
    barrier_();

    // ---- PH1: (mh=0, nh=1) — reads B1; stages A0'', B0'' (tile t+2) ----
    readB(b1, cur, 1);
    if (more2) { stageA(cur, 0, kt2); stageB(cur, 0, kt2); }
    barrier_();
    lgkm0sb();
    mfmaCl(0, 1, b1);
    barrier_();

    // ---- PH2: (mh=1, nh=1) — reads A1; stages B1'' ----
    readA(cur, 1);
    if (more2) stageB(cur, 1, kt2);
    barrier_();
    lgkm0sb();
    mfmaCl(1, 1, b1);
    barrier_();

    // ---- PH3: (mh=1, nh=0) — no reads; stages A1''; ONE wait per tile ----
    if (more2) stageA(cur, 1, kt2);
    barrier_();
    mfmaCl(1, 0, b0);
    if (more2) waitv<TL>(); else waitv<0>();
    barrier_();
  }

  // epilogue: C/D layout col = lane&15, row = (lane>>4)*4 + r
#pragma unroll
  for (int m = 0; m < 8; ++m) {
    const int mh = m >> 2, i = m & 3;
    const long rowg0 = brow + mh * 128 + wm * 64 + i * 16 + kq * 4;
#pragma unroll
    for (int n = 0; n < NREP; ++n) {
      const int nh = n / NPH, j = n % NPH;
      const long colg = bcol + nh * (BN / 2) + wn * (WVN / 2) + j * 16 + fr;
      f32x4 v = acc[m][n];
      bool stored = false;
      if constexpr (std::is_same<OUT_T, unsigned short>::value) {
        if (z == ztrans) {
          // transposed per-batch store: Vt[b][e][s], b from row (2048 rows/b)
          unsigned short* Ct = (unsigned short*)(C + z * sC);
          const long bb = rowg0 >> 11;
          ushort4 pk;
          pk.x = f2bf(v[0] * scale);
          pk.y = f2bf(v[1] * scale);
          pk.z = f2bf(v[2] * scale);
          pk.w = f2bf(v[3] * scale);
          *(ushort4*)(Ct + bb * (2048L * 1024) + colg * 2048 + (rowg0 & 2047)) =
              pk;
          stored = true;
        }
      }
      if (!stored) {
        OUT_T* Cz = C + (long)z * sC;
#pragma unroll
        for (int r = 0; r < 4; ++r) {
          float val = v[r] * scale;
          if constexpr (std::is_same<OUT_T, float>::value)
            Cz[(rowg0 + r) * ldC + colg] = val;
          else
            Cz[(rowg0 + r) * ldC + colg] = f2bf(val);
        }
      }
    }
  }
}

// ---------------- row softmax in-place on bf16 [rows x 2048] ----------------
__global__ __launch_bounds__(256) void softmax_inplace(
    unsigned short* __restrict__ S) {
  unsigned short* row = S + (size_t)blockIdx.x * 2048;
  const int tid = threadIdx.x;
  const int wid = tid >> 6;
  const int lane = tid & 63;

  uint4 raw = *(const uint4*)(row + tid * 8);
  float v[8];
  v[0] = bf2f(raw.x & 0xffff); v[1] = bf2f(raw.x >> 16);
  v[2] = bf2f(raw.y & 0xffff); v[3] = bf2f(raw.y >> 16);
  v[4] = bf2f(raw.z & 0xffff); v[5] = bf2f(raw.z >> 16);
  v[6] = bf2f(raw.w & 0xffff); v[7] = bf2f(raw.w >> 16);

  float mx = v[0];
#pragma unroll
  for (int i = 1; i < 8; ++i) mx = fmaxf(mx, v[i]);
#pragma unroll
  for (int off = 32; off; off >>= 1) mx = fmaxf(mx, __shfl_xor(mx, off));

  __shared__ float sred[8];
  if (lane == 0) sred[wid] = mx;
  __syncthreads();
  mx = fmaxf(fmaxf(sred[0], sred[1]), fmaxf(sred[2], sred[3]));

  float e[8];
  float s = 0.f;
#pragma unroll
  for (int i = 0; i < 8; ++i) {
    e[i] = __expf(v[i] - mx);
    s += e[i];
  }
#pragma unroll
  for (int off = 32; off; off >>= 1) s += __shfl_xor(s, off);
  if (lane == 0) sred[4 + wid] = s;
  __syncthreads();
  s = (sred[4] + sred[5]) + (sred[6] + sred[7]);
  float inv = 1.0f / s;

  uint4 pk;
  pk.x = (uint32_t)f2bf(e[0] * inv) | ((uint32_t)f2bf(e[1] * inv) << 16);
  pk.y = (uint32_t)f2bf(e[2] * inv) | ((uint32_t)f2bf(e[3] * inv) << 16);
  pk.z = (uint32_t)f2bf(e[4] * inv) | ((uint32_t)f2bf(e[5] * inv) << 16);
  pk.w = (uint32_t)f2bf(e[6] * inv) | ((uint32_t)f2bf(e[7] * inv) << 16);
  *(uint4*)(row + tid * 8) = pk;
}

// ---------------------------------------------------------------------------
extern "C" void kernel_launch(void* const* d_in, const int* in_sizes, int n_in,
                              void* d_out, int out_size, void* d_ws,
                              size_t ws_size, hipStream_t stream) {
  const float* x = (const float*)d_in[0];
  const float* Wq = (const float*)d_in[1];
  const float* Wk = (const float*)d_in[2];
  const float* Wv = (const float*)d_in[3];
  float* out = (float*)d_out;

  const long XE = 4L * 2048 * 1024;  // 8,388,608 elems
  const long WE = 1024L * 1024;      // 1,048,576 elems
  const long SE = 4L * 2048 * 2048;  // 16,777,216 elems

  unsigned short* xb = (unsigned short*)d_ws;
  unsigned short* Wqb = xb + XE;     // Wq,Wk,Wv contiguous (strideB = WE)
  unsigned short* Qb = Wqb + 3 * WE; // Qb,Kb,Vtb contiguous (strideC = XE)
  unsigned short* Kb = Qb + XE;
  unsigned short* Vtb = Kb + XE;     // [b][e][s] (transposed V)
  unsigned short* Sb = Vtb + XE;     // [b][q][k] scores -> probs
  if (ws_size < (size_t)(4 * XE + 3 * WE + SE) * 2) return;  // loud failure

  cast_f32_to_bf16<<<1024, 256, 0, stream>>>(x, xb, XE);
  cast_w3<<<1536, 256, 0, stream>>>(Wq, Wk, Wv, Wqb);

  // fused QKV projection: z in {0,1,2} -> Wq/Wk/Wv, C = Qb/Kb/Vtb(z=2 trans).
  // M=8192 (nbm=32), N=1024 (BN=256 -> nbn=4): 32*4*3 = 384 blocks.
  gemm8p<256, unsigned short><<<384, 512, 0, stream>>>(
      xb, Wqb, Qb, 1024, 1024, 1024, 1024, 0, WE, XE, 1.0f, 32, 4,
      /*ztrans=*/2);
  // S[b][q][k] = Qb Kb^T / 32, per batch: 8x8x4 = 256 blocks (256x256 tile)
  gemm8p<256, unsigned short><<<256, 512, 0, stream>>>(
      Qb, Kb, Sb, 1024, 1024, 1024, 2048, 2048L * 1024, 2048L * 1024,
      2048L * 2048, 0.03125f, 8, 8, -1);
  // softmax rows (4*2048 rows of 2048)
  softmax_inplace<<<8192, 256, 0, stream>>>(Sb);
  // out[b][q][e] = P Vt^T, per batch: BN=128 -> 8x8x4 = 256 blocks, fp32 out
  gemm8p<128, float><<<256, 512, 0, stream>>>(
      Sb, Vtb, out, 2048, 2048, 2048, 1024, 2048L * 2048, 1024L * 2048,
      2048L * 1024, 1.0f, 8, 8, -1);
}

// Round 6
// 180.084 us; speedup vs baseline: 1.0020x; 1.0020x over previous
//
#include <hip/hip_runtime.h>
#include <hip/hip_bf16.h>
#include <stdint.h>
#include <type_traits>

// ---------------------------------------------------------------------------
// Fused attention: out = softmax((x Wq^T)(x Wk^T)^T / sqrt(d)) (x Wv^T)
// B=4, S=2048, D=1024, fp32 in/out, bf16 MFMA internal compute.
//
// R6: same 2-tile-lead Gray-code pipeline as R5, but WITHOUT the explicit
// lgkmcnt(0)+sched_barrier(0) before each MFMA cluster: the ds_reads are
// compiler-generated, so the compiler emits fine-grained laddered lgkmcnt
// per MFMA operand (m97 behavior) — first MFMAs start as soon as their own
// operands land, overlapping the LDS pipe (trailing waves' reads) with the
// MFMA pipe (leading waves). WAR safety: every phase's reads complete before
// its barrier#2 (consumed by that phase's MFMAs); stages into those regions
// are issued after that barrier. RAW: counted vmcnt + barrier as before.
// Kernels split into named variants for clean profiling.
// ---------------------------------------------------------------------------

typedef __attribute__((ext_vector_type(8))) short short8;
typedef __attribute__((ext_vector_type(4))) float f32x4;

#define GL_G(p) ((const __attribute__((address_space(1))) void*)(p))
#define GL_L(p) ((__attribute__((address_space(3))) void*)(p))

__device__ __forceinline__ float bf2f(unsigned short u) {
  union { float f; uint32_t i; } c; c.i = ((uint32_t)u) << 16; return c.f;
}
__device__ __forceinline__ unsigned short f2bf(float f) {
  __hip_bfloat16 h = __float2bfloat16(f);
  return *reinterpret_cast<unsigned short*>(&h);
}

// ---------------- cast fp32 -> bf16 (vectorized) ----------------
__global__ __launch_bounds__(256) void cast_f32_to_bf16(
    const float* __restrict__ in, unsigned short* __restrict__ out, long n) {
  long tid = (long)blockIdx.x * blockDim.x + threadIdx.x;
  long stride = (long)gridDim.x * blockDim.x;
  for (long j = tid * 8; j < n; j += stride * 8) {
    float4 a = *(const float4*)(in + j);
    float4 b = *(const float4*)(in + j + 4);
    uint4 pk;
    pk.x = (uint32_t)f2bf(a.x) | ((uint32_t)f2bf(a.y) << 16);
    pk.y = (uint32_t)f2bf(a.z) | ((uint32_t)f2bf(a.w) << 16);
    pk.z = (uint32_t)f2bf(b.x) | ((uint32_t)f2bf(b.y) << 16);
    pk.w = (uint32_t)f2bf(b.z) | ((uint32_t)f2bf(b.w) << 16);
    *(uint4*)(out + j) = pk;
  }
}

// fused 3-weight cast: Wq,Wk,Wv (each WE=2^20 elems) -> contiguous bf16
__global__ __launch_bounds__(256) void cast_w3(
    const float* __restrict__ wq, const float* __restrict__ wk,
    const float* __restrict__ wv, unsigned short* __restrict__ out) {
  const long WE = 1L << 20;
  long j = ((long)blockIdx.x * blockDim.x + threadIdx.x) * 8;
  if (j >= 3 * WE) return;
  int sel = (int)(j >> 20);
  const float* src = (sel == 0) ? wq : (sel == 1) ? wk : wv;
  long loc = j & (WE - 1);
  float4 a = *(const float4*)(src + loc);
  float4 b = *(const float4*)(src + loc + 4);
  uint4 pk;
  pk.x = (uint32_t)f2bf(a.x) | ((uint32_t)f2bf(a.y) << 16);
  pk.y = (uint32_t)f2bf(a.z) | ((uint32_t)f2bf(a.w) << 16);
  pk.z = (uint32_t)f2bf(b.x) | ((uint32_t)f2bf(b.y) << 16);
  pk.w = (uint32_t)f2bf(b.z) | ((uint32_t)f2bf(b.w) << 16);
  *(uint4*)(out + j) = pk;
}

template <int N>
__device__ __forceinline__ void waitv() {
  asm volatile("s_waitcnt vmcnt(%0)" :: "n"(N) : "memory");
}
__device__ __forceinline__ void barrier_() {
  asm volatile("" ::: "memory");
  __builtin_amdgcn_s_barrier();
  asm volatile("" ::: "memory");
}

// ---------------- NT GEMM device body, 256xBN tile, BK=64 ------------------
// C[m,n] = scale * sum_k A[m,k] B[n,k].  A:[M x K] bf16 (ldA), B:[N x K] (ldB)
// Requires M%256==0, N%BN==0, K%64==0, K/64 >= 2. Grid 1D = nbm*nbn*nz, %8==0.
// If z == ztrans (OUT_T must be ushort): store transposed per-batch
// (hardcoded: 2048 rows/batch, out [1024][2048] per batch).
template <int BN, typename OUT_T>
__device__ __forceinline__ void gemm_body(
    const unsigned short* __restrict__ A, const unsigned short* __restrict__ B,
    OUT_T* __restrict__ C, int K, int ldA, int ldB, int ldC,
    long sA, long sB, long sC, float scale, int nbm, int nbn, int ztrans,
    char* smem) {
  constexpr int BM = 256, BK = 64;
  constexpr int WVN = BN / 4;    // per-wave N: 64 or 32
  constexpr int NREP = WVN / 16; // 4 or 2
  constexpr int NPH = NREP / 2;  // frags per phase: 2 or 1
  constexpr int LA = 2;          // global_load_lds per A-half
  constexpr int LB = BN / 128;   // per B-half: 2 or 1
  constexpr int TL = 2 * (LA + LB);        // loads per K-tile (8 or 6)
  constexpr int AHALF = 128 * BK * 2;      // 16384 B
  constexpr int BHALF = (BN / 2) * BK * 2; // 16384 or 8192 B

  const int tid = threadIdx.x;
  const int wid = tid >> 6, lane = tid & 63;
  const int wm = wid >> 2, wn = wid & 3;
  const int fr = lane & 15;
  const int kq = lane >> 4;  // 0..3

  // XCD-aware bijective swizzle (gridDim %8==0), n-major decode.
  const int NB = gridDim.x;
  const int p = blockIdx.x;
  const int l = (p & 7) * (NB >> 3) + (p >> 3);
  const int pb = nbm * nbn;
  const int z = l / pb;
  const int mn = l - z * pb;
  const int bm = mn / nbn, bn = mn - bm * nbn;
  const unsigned short* Az = A + (long)z * sA;
  const unsigned short* Bz = B + (long)z * sB;
  const long brow = (long)bm * BM, bcol = (long)bn * BN;

  // staging: each load = 512 thr x 16B = 64 rows x 128B. source col is
  // pre-swizzled so linear LDS write == swizzled layout (m173/m201 pattern).
  const int srow = tid >> 3;  // 0..63
  const int scolb = ((tid & 7) * 16) ^ ((srow & 7) << 4);

  auto stageA = [&](int buf, int half, int kt) {
#pragma unroll
    for (int part = 0; part < LA; ++part) {
      const char* g = (const char*)Az +
          ((brow + half * 128 + part * 64 + srow) * (long)ldA + kt) * 2 + scolb;
      __builtin_amdgcn_global_load_lds(
          GL_G(g),
          GL_L(smem + (buf * 2 + half) * AHALF + part * 8192 + wid * 1024),
          16, 0, 0);
    }
  };
  auto stageB = [&](int buf, int half, int kt) {
#pragma unroll
    for (int part = 0; part < LB; ++part) {
      const char* g = (const char*)Bz +
          ((bcol + half * (BN / 2) + part * 64 + srow) * (long)ldB + kt) * 2 +
          scolb;
      __builtin_amdgcn_global_load_lds(
          GL_G(g),
          GL_L(smem + 4 * AHALF + (buf * 2 + half) * BHALF + part * 8192 +
               wid * 1024),
          16, 0, 0);
    }
  };

  f32x4 acc[8][NREP];
#pragma unroll
  for (int m = 0; m < 8; ++m)
#pragma unroll
    for (int n = 0; n < NREP; ++n) acc[m][n] = (f32x4){0.f, 0.f, 0.f, 0.f};

  short8 af[4][2];         // current A-half (reloaded ph0 / ph2)
  short8 b0[NPH][2];       // B-half 0 (read ph0, reused ph3)
  short8 b1[NPH][2];       // B-half 1 (read ph1, reused ph2)

  auto readA = [&](int cur, int mh) {
#pragma unroll
    for (int i = 0; i < 4; ++i)
#pragma unroll
      for (int ks = 0; ks < 2; ++ks) {
        const int r = wm * 64 + i * 16 + fr;
        const int off = (cur * 2 + mh) * AHALF + r * 128 +
                        ((ks * 64 + kq * 16) ^ ((fr & 7) << 4));
        af[i][ks] = *(const short8*)(smem + off);
      }
  };
  auto readB = [&](short8 (&bf_)[NPH][2], int cur, int nh) {
#pragma unroll
    for (int j = 0; j < NPH; ++j)
#pragma unroll
      for (int ks = 0; ks < 2; ++ks) {
        const int r = wn * (WVN / 2) + j * 16 + fr;
        const int off = 4 * AHALF + (cur * 2 + nh) * BHALF + r * 128 +
                        ((ks * 64 + kq * 16) ^ ((fr & 7) << 4));
        bf_[j][ks] = *(const short8*)(smem + off);
      }
  };
  auto mfmaCl = [&](int mh, int nh, short8 (&bf_)[NPH][2]) {
    __builtin_amdgcn_s_setprio(1);
#pragma unroll
    for (int i = 0; i < 4; ++i)
#pragma unroll
      for (int j = 0; j < NPH; ++j)
#pragma unroll
        for (int ks = 0; ks < 2; ++ks)
          acc[mh * 4 + i][nh * NPH + j] =
              __builtin_amdgcn_mfma_f32_16x16x32_bf16(
                  af[i][ks], bf_[j][ks], acc[mh * 4 + i][nh * NPH + j], 0, 0,
                  0);
    __builtin_amdgcn_s_setprio(0);
  };

  // prologue: tiles 0 and 1 staged (buf0, buf1); drain tile 0 (vmcnt(TL)
  // leaves tile 1's TL loads in flight).
  stageA(0, 0, 0); stageB(0, 0, 0); stageB(0, 1, 0); stageA(0, 1, 0);
  stageA(1, 0, BK); stageB(1, 0, BK); stageB(1, 1, BK); stageA(1, 1, BK);
  waitv<TL>();
  barrier_();

  const int nt = K / BK;  // >= 2 required
  for (int t = 0; t < nt; ++t) {
    const int cur = t & 1;
    const int kt2 = (t + 2) * BK;
    const bool more2 = (t + 2) < nt;

    // ---- PH0: (mh=0, nh=0) — reads A0, B0 ----
    readA(cur, 0);
    readB(b0, cur, 0);
    barrier_();
    mfmaCl(0, 0, b0);
    barrier_();

    // ---- PH1: (mh=0, nh=1) — reads B1; stages A0'', B0'' (tile t+2) ----
    readB(b1, cur, 1);
    if (more2) { stageA(cur, 0, kt2); stageB(cur, 0, kt2); }
    barrier_();
    mfmaCl(0, 1, b1);
    barrier_();

    // ---- PH2: (mh=1, nh=1) — reads A1; stages B1'' ----
    readA(cur, 1);
    if (more2) stageB(cur, 1, kt2);
    barrier_();
    mfmaCl(1, 1, b1);
    barrier_();

    // ---- PH3: (mh=1, nh=0) — no reads; stages A1''; ONE wait per tile ----
    if (more2) stageA(cur, 1, kt2);
    barrier_();
    mfmaCl(1, 0, b0);
    if (more2) waitv<TL>(); else waitv<0>();
    barrier_();
  }

  // epilogue: C/D layout col = lane&15, row = (lane>>4)*4 + r
#pragma unroll
  for (int m = 0; m < 8; ++m) {
    const int mh = m >> 2, i = m & 3;
    const long rowg0 = brow + mh * 128 + wm * 64 + i * 16 + kq * 4;
#pragma unroll
    for (int n = 0; n < NREP; ++n) {
      const int nh = n / NPH, j = n % NPH;
      const long colg = bcol + nh * (BN / 2) + wn * (WVN / 2) + j * 16 + fr;
      f32x4 v = acc[m][n];
      bool stored = false;
      if constexpr (std::is_same<OUT_T, unsigned short>::value) {
        if (z == ztrans) {
          // transposed per-batch store: Vt[b][e][s], b from row (2048 rows/b)
          unsigned short* Ct = (unsigned short*)(C + z * sC);
          const long bb = rowg0 >> 11;
          ushort4 pk;
          pk.x = f2bf(v[0] * scale);
          pk.y = f2bf(v[1] * scale);
          pk.z = f2bf(v[2] * scale);
          pk.w = f2bf(v[3] * scale);
          *(ushort4*)(Ct + bb * (2048L * 1024) + colg * 2048 + (rowg0 & 2047)) =
              pk;
          stored = true;
        }
      }
      if (!stored) {
        OUT_T* Cz = C + (long)z * sC;
#pragma unroll
        for (int r = 0; r < 4; ++r) {
          float val = v[r] * scale;
          if constexpr (std::is_same<OUT_T, float>::value)
            Cz[(rowg0 + r) * ldC + colg] = val;
          else
            Cz[(rowg0 + r) * ldC + colg] = f2bf(val);
        }
      }
    }
  }
}

// named kernel wrappers (distinct profile rows)
__global__ __launch_bounds__(512, 2) void gemm_proj(
    const unsigned short* __restrict__ A, const unsigned short* __restrict__ B,
    unsigned short* __restrict__ C, int K, int ldA, int ldB, int ldC,
    long sA, long sB, long sC, float scale, int nbm, int nbn, int ztrans) {
  __shared__ __align__(16) char smem[131072];
  gemm_body<256, unsigned short>(A, B, C, K, ldA, ldB, ldC, sA, sB, sC, scale,
                                 nbm, nbn, ztrans, smem);
}
__global__ __launch_bounds__(512, 2) void gemm_scores(
    const unsigned short* __restrict__ A, const unsigned short* __restrict__ B,
    unsigned short* __restrict__ C, int K, int ldA, int ldB, int ldC,
    long sA, long sB, long sC, float scale, int nbm, int nbn, int ztrans) {
  __shared__ __align__(16) char smem[131072];
  gemm_body<256, unsigned short>(A, B, C, K, ldA, ldB, ldC, sA, sB, sC, scale,
                                 nbm, nbn, ztrans, smem);
}
__global__ __launch_bounds__(512, 2) void gemm_pv(
    const unsigned short* __restrict__ A, const unsigned short* __restrict__ B,
    float* __restrict__ C, int K, int ldA, int ldB, int ldC,
    long sA, long sB, long sC, float scale, int nbm, int nbn, int ztrans) {
  __shared__ __align__(16) char smem[98304];
  gemm_body<128, float>(A, B, C, K, ldA, ldB, ldC, sA, sB, sC, scale,
                        nbm, nbn, ztrans, smem);
}

// ---------------- row softmax in-place on bf16 [rows x 2048] ----------------
__global__ __launch_bounds__(256) void softmax_inplace(
    unsigned short* __restrict__ S) {
  unsigned short* row = S + (size_t)blockIdx.x * 2048;
  const int tid = threadIdx.x;
  const int wid = tid >> 6;
  const int lane = tid & 63;

  uint4 raw = *(const uint4*)(row + tid * 8);
  float v[8];
  v[0] = bf2f(raw.x & 0xffff); v[1] = bf2f(raw.x >> 16);
  v[2] = bf2f(raw.y & 0xffff); v[3] = bf2f(raw.y >> 16);
  v[4] = bf2f(raw.z & 0xffff); v[5] = bf2f(raw.z >> 16);
  v[6] = bf2f(raw.w & 0xffff); v[7] = bf2f(raw.w >> 16);

  float mx = v[0];
#pragma unroll
  for (int i = 1; i < 8; ++i) mx = fmaxf(mx, v[i]);
#pragma unroll
  for (int off = 32; off; off >>= 1) mx = fmaxf(mx, __shfl_xor(mx, off));

  __shared__ float sred[8];
  if (lane == 0) sred[wid] = mx;
  __syncthreads();
  mx = fmaxf(fmaxf(sred[0], sred[1]), fmaxf(sred[2], sred[3]));

  float e[8];
  float s = 0.f;
#pragma unroll
  for (int i = 0; i < 8; ++i) {
    e[i] = __expf(v[i] - mx);
    s += e[i];
  }
#pragma unroll
  for (int off = 32; off; off >>= 1) s += __shfl_xor(s, off);
  if (lane == 0) sred[4 + wid] = s;
  __syncthreads();
  s = (sred[4] + sred[5]) + (sred[6] + sred[7]);
  float inv = 1.0f / s;

  uint4 pk;
  pk.x = (uint32_t)f2bf(e[0] * inv) | ((uint32_t)f2bf(e[1] * inv) << 16);
  pk.y = (uint32_t)f2bf(e[2] * inv) | ((uint32_t)f2bf(e[3] * inv) << 16);
  pk.z = (uint32_t)f2bf(e[4] * inv) | ((uint32_t)f2bf(e[5] * inv) << 16);
  pk.w = (uint32_t)f2bf(e[6] * inv) | ((uint32_t)f2bf(e[7] * inv) << 16);
  *(uint4*)(row + tid * 8) = pk;
}

// ---------------------------------------------------------------------------
extern "C" void kernel_launch(void* const* d_in, const int* in_sizes, int n_in,
                              void* d_out, int out_size, void* d_ws,
                              size_t ws_size, hipStream_t stream) {
  const float* x = (const float*)d_in[0];
  const float* Wq = (const float*)d_in[1];
  const float* Wk = (const float*)d_in[2];
  const float* Wv = (const float*)d_in[3];
  float* out = (float*)d_out;

  const long XE = 4L * 2048 * 1024;  // 8,388,608 elems
  const long WE = 1024L * 1024;      // 1,048,576 elems
  const long SE = 4L * 2048 * 2048;  // 16,777,216 elems

  unsigned short* xb = (unsigned short*)d_ws;
  unsigned short* Wqb = xb + XE;     // Wq,Wk,Wv contiguous (strideB = WE)
  unsigned short* Qb = Wqb + 3 * WE; // Qb,Kb,Vtb contiguous (strideC = XE)
  unsigned short* Kb = Qb + XE;
  unsigned short* Vtb = Kb + XE;     // [b][e][s] (transposed V)
  unsigned short* Sb = Vtb + XE;     // [b][q][k] scores -> probs
  if (ws_size < (size_t)(4 * XE + 3 * WE + SE) * 2) return;  // loud failure

  cast_f32_to_bf16<<<1024, 256, 0, stream>>>(x, xb, XE);
  cast_w3<<<1536, 256, 0, stream>>>(Wq, Wk, Wv, Wqb);

  // fused QKV projection: z in {0,1,2} -> Wq/Wk/Wv, C = Qb/Kb/Vtb(z=2 trans).
  // M=8192 (nbm=32), N=1024 (BN=256 -> nbn=4): 32*4*3 = 384 blocks.
  gemm_proj<<<384, 512, 0, stream>>>(
      xb, Wqb, Qb, 1024, 1024, 1024, 1024, 0, WE, XE, 1.0f, 32, 4,
      /*ztrans=*/2);
  // S[b][q][k] = Qb Kb^T / 32, per batch: 8x8x4 = 256 blocks (256x256 tile)
  gemm_scores<<<256, 512, 0, stream>>>(
      Qb, Kb, Sb, 1024, 1024, 1024, 2048, 2048L * 1024, 2048L * 1024,
      2048L * 2048, 0.03125f, 8, 8, -1);
  // softmax rows (4*2048 rows of 2048)
  softmax_inplace<<<8192, 256, 0, stream>>>(Sb);
  // out[b][q][e] = P Vt^T, per batch: BN=128 -> 8x8x4 = 256 blocks, fp32 out
  gemm_pv<<<256, 512, 0, stream>>>(
      Sb, Vtb, out, 2048, 2048, 2048, 1024, 2048L * 2048, 1024L * 2048,
      2048L * 1024, 1.0f, 8, 8, -1);
}